// Round 15
// baseline (1290.135 us; speedup 1.0000x reference)
//
#include <hip/hip_runtime.h>
#include <math.h>

// Problem constants (fixed by reference setup_inputs)
#define N_NODES 262144      // S*T
#define SSTMT   16384
#define TT      16
#define DD      128
#define HH      3
#define HD      384         // H*D
#define EPSV    1e-5f

typedef __attribute__((ext_vector_type(8))) short short8v;
typedef __attribute__((ext_vector_type(4))) float f32x4;

// ---------------------------------------------------------------------------
// bf16 split helpers (RNE)
// ---------------------------------------------------------------------------
__device__ __forceinline__ short bf16rne(float x){
    unsigned u = __float_as_uint(x);
    unsigned r = (u + 0x7FFFu + ((u >> 16) & 1u)) >> 16;
    return (short)r;
}
__device__ __forceinline__ float bf2f(short s){
    return __uint_as_float(((unsigned)(unsigned short)s) << 16);
}

// ---------------------------------------------------------------------------
// Prep: split W0 (fp32 [128][384]) into 3 TRANSPOSED bf16 planes
// w0t[p][c][k], p stride 49152 shorts. B-fragments then read contiguous k.
// ---------------------------------------------------------------------------
__global__ __launch_bounds__(128)
void prep_w0t(const float* __restrict__ W0, short* __restrict__ w0t)
{
    int c = blockIdx.x;      // 0..383
    int k = threadIdx.x;     // 0..127
    float v = W0[(size_t)k * HD + c];
    short hi = bf16rne(v);
    float r1 = v - bf2f(hi);
    short mi = bf16rne(r1);
    float r2 = r1 - bf2f(mi);
    short lo = bf16rne(r2);
    size_t idx = (size_t)c * 128 + k;
    w0t[idx]          = hi;
    w0t[49152 + idx]  = mi;
    w0t[98304 + idx]  = lo;
}

// ---------------------------------------------------------------------------
// Pass 1 (MFMA): layer-0 forward for BN0 statistics only.
// 256 thr / 64 rows per block. x staged as 3 swizzled bf16 planes in LDS.
// GEMM0 = 6-product bf16x3 MFMA (fp32-grade, 2^-24). Per 32-row half:
// MFMA -> hbuf(fp32) -> attention (r3-proven fp32 path) -> stats.
// LDS 65.5KB -> 2 blocks/CU. VGPR ~80 (no spill at 128 cap).
// ---------------------------------------------------------------------------
__global__ __launch_bounds__(256, 2)
void gat0_stats_mfma(const float* __restrict__ x, const short* __restrict__ w0t,
                     const float* __restrict__ as0, const float* __restrict__ ad0,
                     const float* __restrict__ b0, float* __restrict__ pA0)
{
    __shared__ short xpl[3][64][128];      // 48KB swizzled bf16 planes
    __shared__ float hbuf[32][128];        // 16KB per-half fp32 h (also stats scratch)
    __shared__ float avs[128], avd[128];
    __shared__ float als[32], ald[32], aSw[32], aNw[32];

    const int tid = threadIdx.x;
    const int bid = blockIdx.x;
    const size_t rb = (size_t)bid * 64;
    const int l = tid & 63;
    const int w = tid >> 6;                // wave 0..3

    // ---- stage x -> 3 swizzled bf16 planes (64 rows, 8-elem chunks) ----
    for (int ch = 0; ch < 4; ++ch) {
        int gi = ch * 256 + tid;           // 0..1023 chunks
        int row = gi >> 4;                 // 0..63
        int c8 = (gi & 15) * 8;
        const float* xp = x + (rb + row) * DD + c8;
        short8v hi, mi, lo;
        #pragma unroll
        for (int j = 0; j < 8; ++j) {
            float v = xp[j];
            short h_ = bf16rne(v);
            float r1 = v - bf2f(h_);
            short m_ = bf16rne(r1);
            float r2 = r1 - bf2f(m_);
            hi[j] = h_; mi[j] = m_; lo[j] = bf16rne(r2);
        }
        int dc = c8 ^ ((row & 7) << 3);    // swizzle in 8-elem units
        *reinterpret_cast<short8v*>(&xpl[0][row][dc]) = hi;
        *reinterpret_cast<short8v*>(&xpl[1][row][dc]) = mi;
        *reinterpret_cast<short8v*>(&xpl[2][row][dc]) = lo;
    }
    __syncthreads();

    const int mt  = w & 1;                 // tile-row within 32-row half
    const int nt0 = (w >> 1) * 4;          // 4 tile-cols per wave
    const int arow_l = mt * 16 + (l & 15);
    const int akb = (l >> 4) * 8;
    const int bl16 = l & 15;
    const int bk   = (l >> 4) * 8;

    for (int h = 0; h < HH; ++h) {
        if (tid < 128) { avs[tid] = as0[h * DD + tid]; avd[tid] = ad0[h * DD + tid]; }
        float ps[4] = {0, 0, 0, 0}, pq[4] = {0, 0, 0, 0};

        for (int half = 0; half < 2; ++half) {
            const int arow = half * 32 + arow_l;

            f32x4 acc[4];
            #pragma unroll
            for (int t = 0; t < 4; ++t) acc[t] = (f32x4){0.f, 0.f, 0.f, 0.f};

            #pragma unroll
            for (int kc = 0; kc < 4; ++kc) {
                int ke = kc * 32 + akb;
                int sc_ = ke ^ ((arow & 7) << 3);
                short8v ahi = *reinterpret_cast<const short8v*>(&xpl[0][arow][sc_]);
                short8v ami = *reinterpret_cast<const short8v*>(&xpl[1][arow][sc_]);
                short8v alo = *reinterpret_cast<const short8v*>(&xpl[2][arow][sc_]);
                #pragma unroll
                for (int t = 0; t < 4; ++t) {
                    int bcol = h * DD + (nt0 + t) * 16 + bl16;
                    const short* bb = w0t + (size_t)bcol * 128 + kc * 32 + bk;
                    short8v bhi = *reinterpret_cast<const short8v*>(bb);
                    short8v bmi = *reinterpret_cast<const short8v*>(bb + 49152);
                    short8v blo = *reinterpret_cast<const short8v*>(bb + 98304);
                    acc[t] = __builtin_amdgcn_mfma_f32_16x16x32_bf16(ahi, bhi, acc[t], 0, 0, 0);
                    acc[t] = __builtin_amdgcn_mfma_f32_16x16x32_bf16(ahi, bmi, acc[t], 0, 0, 0);
                    acc[t] = __builtin_amdgcn_mfma_f32_16x16x32_bf16(ami, bhi, acc[t], 0, 0, 0);
                    acc[t] = __builtin_amdgcn_mfma_f32_16x16x32_bf16(ahi, blo, acc[t], 0, 0, 0);
                    acc[t] = __builtin_amdgcn_mfma_f32_16x16x32_bf16(ami, bmi, acc[t], 0, 0, 0);
                    acc[t] = __builtin_amdgcn_mfma_f32_16x16x32_bf16(alo, bhi, acc[t], 0, 0, 0);
                }
            }

            // write C tiles -> hbuf (C/D layout: col=lane&15, row=(lane>>4)*4+reg)
            __syncthreads();               // hbuf free (prev consumers done)
            #pragma unroll
            for (int t = 0; t < 4; ++t) {
                int col = (nt0 + t) * 16 + (l & 15);
                int rw = mt * 16 + (l >> 4) * 4;
                hbuf[rw + 0][col] = acc[t][0];
                hbuf[rw + 1][col] = acc[t][1];
                hbuf[rw + 2][col] = acc[t][2];
                hbuf[rw + 3][col] = acc[t][3];
            }
            __syncthreads();

            // attention logits + softmax (32-row statement-closed half)
            if (tid < 64) {
                int r = tid & 31;
                const float* av = (tid < 32) ? avs : avd;
                float s = 0.f;
                #pragma unroll 8
                for (int cc = 0; cc < 128; ++cc) {
                    int c = (cc + r * 4) & 127;
                    s += hbuf[r][c] * av[c];
                }
                if (tid < 32) als[r] = s; else ald[r] = s;
            }
            __syncthreads();
            if (tid < 32) {
                int r = tid;
                float es = als[r] + ald[r];
                es = es > 0.f ? es : 0.2f * es;
                float aSv = 1.f, aNv = 0.f;
                if ((r & 15) != 15) {
                    float en = als[r + 1] + ald[r];
                    en = en > 0.f ? en : 0.2f * en;
                    float mx = fmaxf(es, en);
                    float e1 = expf(es - mx), e2 = expf(en - mx);
                    float dn = e1 + e2;
                    aSv = e1 / dn; aNv = e2 / dn;
                }
                aSw[r] = aSv; aNw[r] = aNv;
            }
            __syncthreads();

            // aggregate + bias + relu -> stats
            {
                int rg = tid >> 5, c4g = (tid & 31) * 4;
                float4 bb4 = *reinterpret_cast<const float4*>(&b0[h * DD + c4g]);
                float bbv[4] = {bb4.x, bb4.y, bb4.z, bb4.w};
                #pragma unroll
                for (int i = 0; i < 4; ++i) {
                    int r = rg * 4 + i;
                    float a_s = aSw[r], a_n = aNw[r];
                    bool hasn = ((r & 15) != 15);
                    #pragma unroll
                    for (int j = 0; j < 4; ++j) {
                        float v = hbuf[r][c4g + j];
                        if (hasn) v = a_s * v + a_n * hbuf[r + 1][c4g + j];
                        float o = fmaxf(v + bbv[j], 0.f);
                        ps[j] += o; pq[j] += o * o;
                    }
                }
            }
        }

        // flush head stats through hbuf scratch (4096 floats, need 2048)
        float* bna = &hbuf[0][0];
        __syncthreads();                   // aggregation reads done
        {
            int rg = tid >> 5, c4g = (tid & 31) * 4;
            #pragma unroll
            for (int j = 0; j < 4; ++j) {
                bna[rg * 128 + c4g + j] = ps[j];
                bna[1024 + rg * 128 + c4g + j] = pq[j];
            }
        }
        __syncthreads();
        if (tid < 128) {
            float s = 0.f, q = 0.f;
            #pragma unroll
            for (int g = 0; g < 8; ++g) { s += bna[g * 128 + tid]; q += bna[1024 + g * 128 + tid]; }
            size_t idx = ((size_t)bid * HD + h * DD + tid) * 2;
            pA0[idx] = s; pA0[idx + 1] = q;
        }
    }
}

// ===========================================================================
// gat1_recomp and helpers: byte-identical to round 14 (best measured: 745us)
// ===========================================================================
__device__ __forceinline__ int swzc(int row, int c) { return c ^ (((row >> 3) & 3) << 2); }

template<int NTHR>
__device__ __forceinline__ void stageSwz(float (*dst)[DD], const float* __restrict__ src)
{
    const int tid = threadIdx.x;
    #pragma unroll
    for (int j = 0; j < 2048 / NTHR; ++j) {
        int gi = j * NTHR + tid;
        int row = gi >> 5;
        int c4 = (gi & 31) * 4;
        *reinterpret_cast<float4*>(&dst[row][swzc(row, c4)]) =
            *reinterpret_cast<const float4*>(&src[(size_t)row * DD + c4]);
    }
}

template<int BSTR, int KLEN>
__device__ __forceinline__ void gemm8x8(const float (*A)[DD], const float* __restrict__ Bbase,
                                        int kbeg, int rr, int pad, float acc[8][8])
{
    const float* bp = Bbase + (size_t)kbeg * BSTR;
    const float* ar = &A[rr * 8][0];
    #pragma unroll 2
    for (int k = 0; k < KLEN; k += 4) {
        float4 b00 = *reinterpret_cast<const float4*>(bp);
        float4 b01 = *reinterpret_cast<const float4*>(bp + 4);
        float4 b10 = *reinterpret_cast<const float4*>(bp + BSTR);
        float4 b11 = *reinterpret_cast<const float4*>(bp + BSTR + 4);
        float4 b20 = *reinterpret_cast<const float4*>(bp + 2 * BSTR);
        float4 b21 = *reinterpret_cast<const float4*>(bp + 2 * BSTR + 4);
        float4 b30 = *reinterpret_cast<const float4*>(bp + 3 * BSTR);
        float4 b31 = *reinterpret_cast<const float4*>(bp + 3 * BSTR + 4);
        bp += 4 * (size_t)BSTR;
        const int pc = (kbeg + k) ^ pad;
        #pragma unroll
        for (int i = 0; i < 8; ++i) {
            float4 a = *reinterpret_cast<const float4*>(ar + i * DD + pc);
            acc[i][0] += a.x*b00.x; acc[i][1] += a.x*b00.y; acc[i][2] += a.x*b00.z; acc[i][3] += a.x*b00.w;
            acc[i][4] += a.x*b01.x; acc[i][5] += a.x*b01.y; acc[i][6] += a.x*b01.z; acc[i][7] += a.x*b01.w;
            acc[i][0] += a.y*b10.x; acc[i][1] += a.y*b10.y; acc[i][2] += a.y*b10.z; acc[i][3] += a.y*b10.w;
            acc[i][4] += a.y*b11.x; acc[i][5] += a.y*b11.y; acc[i][6] += a.y*b11.z; acc[i][7] += a.y*b11.w;
            acc[i][0] += a.z*b20.x; acc[i][1] += a.z*b20.y; acc[i][2] += a.z*b20.z; acc[i][3] += a.z*b20.w;
            acc[i][4] += a.z*b21.x; acc[i][5] += a.z*b21.y; acc[i][6] += a.z*b21.z; acc[i][7] += a.z*b21.w;
            acc[i][0] += a.w*b30.x; acc[i][1] += a.w*b30.y; acc[i][2] += a.w*b30.z; acc[i][3] += a.w*b30.w;
            acc[i][4] += a.w*b31.x; acc[i][5] += a.w*b31.y; acc[i][6] += a.w*b31.z; acc[i][7] += a.w*b31.w;
        }
    }
}

__device__ __forceinline__ void attnAgg(float acc[8][8],
                                        const float* __restrict__ avsP,
                                        const float* __restrict__ avdP,
                                        const float* __restrict__ bP, int rr)
{
    float4 s0 = *reinterpret_cast<const float4*>(avsP);
    float4 s1 = *reinterpret_cast<const float4*>(avsP + 4);
    float4 d0 = *reinterpret_cast<const float4*>(avdP);
    float4 d1 = *reinterpret_cast<const float4*>(avdP + 4);
    float als[8], ald[8];
    #pragma unroll
    for (int i = 0; i < 8; ++i) {
        als[i] = acc[i][0]*s0.x + acc[i][1]*s0.y + acc[i][2]*s0.z + acc[i][3]*s0.w
               + acc[i][4]*s1.x + acc[i][5]*s1.y + acc[i][6]*s1.z + acc[i][7]*s1.w;
        ald[i] = acc[i][0]*d0.x + acc[i][1]*d0.y + acc[i][2]*d0.z + acc[i][3]*d0.w
               + acc[i][4]*d1.x + acc[i][5]*d1.y + acc[i][6]*d1.z + acc[i][7]*d1.w;
    }
    #pragma unroll
    for (int m = 1; m <= 8; m <<= 1) {
        #pragma unroll
        for (int i = 0; i < 8; ++i) {
            als[i] += __shfl_xor(als[i], m);
            ald[i] += __shfl_xor(ald[i], m);
        }
    }
    float alsN = __shfl_down(als[0], 16);
    float accN[8];
    #pragma unroll
    for (int j = 0; j < 8; ++j) accN[j] = __shfl_down(acc[0][j], 16);

    float4 bb0 = *reinterpret_cast<const float4*>(bP);
    float4 bb1 = *reinterpret_cast<const float4*>(bP + 4);
    float bbv[8] = {bb0.x, bb0.y, bb0.z, bb0.w, bb1.x, bb1.y, bb1.z, bb1.w};
    const bool tail7 = (rr & 1);
    #pragma unroll
    for (int i = 0; i < 8; ++i) {
        float es = als[i] + ald[i];
        es = es > 0.f ? es : 0.2f * es;
        float aS = 1.f, aN = 0.f;
        if (!(tail7 && i == 7)) {
            float en = ((i < 7) ? als[i + 1] : alsN) + ald[i];
            en = en > 0.f ? en : 0.2f * en;
            float mx = fmaxf(es, en);
            float e1 = expf(es - mx), e2 = expf(en - mx);
            float den = e1 + e2;
            aS = e1 / den; aN = e2 / den;
        }
        #pragma unroll
        for (int j = 0; j < 8; ++j) {
            float nb = (i < 7) ? acc[i + 1][j] : accN[j];
            acc[i][j] = fmaxf(aS * acc[i][j] + aN * nb + bbv[j], 0.f);
        }
    }
}

__global__ __launch_bounds__(256, 2)
void gat1_recomp(const float* __restrict__ x, const float* __restrict__ W0,
                 const float* __restrict__ as0, const float* __restrict__ ad0,
                 const float* __restrict__ b0, const float* __restrict__ sc0,
                 const float* __restrict__ sh0, const float* __restrict__ W1,
                 const float* __restrict__ as1, const float* __restrict__ ad1,
                 const float* __restrict__ b1,
                 float* __restrict__ r1, float* __restrict__ pA1)
{
    __shared__ float xs[64][DD];
    __shared__ float hs[64][DD];
    __shared__ float bps[8][DD], bqs[8][DD];

    const int tid = threadIdx.x;
    const int bid = blockIdx.x;
    const int kh = tid >> 7;
    const int rr = (tid >> 4) & 7;
    const int cg = tid & 15;
    const int pad = (rr & 3) << 2;
    const size_t rb = (size_t)bid * 64;
    const bool finisher = (kh == ((rr >= 4) ? 1 : 0));

    stageSwz<256>(xs, x + rb * DD);
    __syncthreads();

    float acc2[8][8];
    #pragma unroll
    for (int i = 0; i < 8; ++i)
        #pragma unroll
        for (int j = 0; j < 8; ++j) acc2[i][j] = 0.f;

    for (int h = 0; h < HH; ++h) {
        float acc[8][8];
        #pragma unroll
        for (int i = 0; i < 8; ++i)
            #pragma unroll
            for (int j = 0; j < 8; ++j) acc[i][j] = 0.f;

        gemm8x8<HD, 64>(xs, W0 + h * DD + cg * 8, kh * 64, rr, pad, acc);

        __syncthreads();
        if (!finisher) {
            #pragma unroll
            for (int i = 0; i < 8; ++i) {
                int pc = (cg * 8) ^ pad;
                *reinterpret_cast<float4*>(&hs[rr * 8 + i][pc]) =
                    make_float4(acc[i][0], acc[i][1], acc[i][2], acc[i][3]);
                *reinterpret_cast<float4*>(&hs[rr * 8 + i][pc ^ 4]) =
                    make_float4(acc[i][4], acc[i][5], acc[i][6], acc[i][7]);
            }
        }
        __syncthreads();
        if (finisher) {
            #pragma unroll
            for (int i = 0; i < 8; ++i) {
                int pc = (cg * 8) ^ pad;
                float4 p0 = *reinterpret_cast<const float4*>(&hs[rr * 8 + i][pc]);
                float4 p1 = *reinterpret_cast<const float4*>(&hs[rr * 8 + i][pc ^ 4]);
                acc[i][0] += p0.x; acc[i][1] += p0.y; acc[i][2] += p0.z; acc[i][3] += p0.w;
                acc[i][4] += p1.x; acc[i][5] += p1.y; acc[i][6] += p1.z; acc[i][7] += p1.w;
            }
            attnAgg(acc, as0 + h * DD + cg * 8, ad0 + h * DD + cg * 8, b0 + h * DD + cg * 8, rr);
            float4 sc0a = *reinterpret_cast<const float4*>(&sc0[h * DD + cg * 8]);
            float4 sc0b = *reinterpret_cast<const float4*>(&sc0[h * DD + cg * 8 + 4]);
            float4 sh0a = *reinterpret_cast<const float4*>(&sh0[h * DD + cg * 8]);
            float4 sh0b = *reinterpret_cast<const float4*>(&sh0[h * DD + cg * 8 + 4]);
            float scv[8] = {sc0a.x, sc0a.y, sc0a.z, sc0a.w, sc0b.x, sc0b.y, sc0b.z, sc0b.w};
            float shv[8] = {sh0a.x, sh0a.y, sh0a.z, sh0a.w, sh0b.x, sh0b.y, sh0b.z, sh0b.w};
            #pragma unroll
            for (int i = 0; i < 8; ++i) {
                int pc = (cg * 8) ^ pad;
                float v0 = acc[i][0] * scv[0] + shv[0];
                float v1 = acc[i][1] * scv[1] + shv[1];
                float v2 = acc[i][2] * scv[2] + shv[2];
                float v3 = acc[i][3] * scv[3] + shv[3];
                float v4 = acc[i][4] * scv[4] + shv[4];
                float v5 = acc[i][5] * scv[5] + shv[5];
                float v6 = acc[i][6] * scv[6] + shv[6];
                float v7 = acc[i][7] * scv[7] + shv[7];
                *reinterpret_cast<float4*>(&hs[rr * 8 + i][pc]) = make_float4(v0, v1, v2, v3);
                *reinterpret_cast<float4*>(&hs[rr * 8 + i][pc ^ 4]) = make_float4(v4, v5, v6, v7);
            }
        }
        __syncthreads();

        gemm8x8<DD, 64>(hs, W1 + (size_t)(h * DD) * DD + cg * 8, kh * 64, rr, pad, acc2);
    }

    __syncthreads();
    if (!finisher) {
        #pragma unroll
        for (int i = 0; i < 8; ++i) {
            int pc = (cg * 8) ^ pad;
            *reinterpret_cast<float4*>(&xs[rr * 8 + i][pc]) =
                make_float4(acc2[i][0], acc2[i][1], acc2[i][2], acc2[i][3]);
            *reinterpret_cast<float4*>(&xs[rr * 8 + i][pc ^ 4]) =
                make_float4(acc2[i][4], acc2[i][5], acc2[i][6], acc2[i][7]);
        }
    }
    __syncthreads();
    if (finisher) {
        #pragma unroll
        for (int i = 0; i < 8; ++i) {
            int pc = (cg * 8) ^ pad;
            float4 p0 = *reinterpret_cast<const float4*>(&xs[rr * 8 + i][pc]);
            float4 p1 = *reinterpret_cast<const float4*>(&xs[rr * 8 + i][pc ^ 4]);
            acc2[i][0] += p0.x; acc2[i][1] += p0.y; acc2[i][2] += p0.z; acc2[i][3] += p0.w;
            acc2[i][4] += p1.x; acc2[i][5] += p1.y; acc2[i][6] += p1.z; acc2[i][7] += p1.w;
        }
        attnAgg(acc2, as1 + cg * 8, ad1 + cg * 8, b1 + cg * 8, rr);

        float ps[8], pq[8];
        #pragma unroll
        for (int j = 0; j < 8; ++j) { ps[j] = 0.f; pq[j] = 0.f; }
        #pragma unroll
        for (int i = 0; i < 8; ++i) {
            *reinterpret_cast<float4*>(&r1[(rb + rr * 8 + i) * DD + cg * 8]) =
                make_float4(acc2[i][0], acc2[i][1], acc2[i][2], acc2[i][3]);
            *reinterpret_cast<float4*>(&r1[(rb + rr * 8 + i) * DD + cg * 8 + 4]) =
                make_float4(acc2[i][4], acc2[i][5], acc2[i][6], acc2[i][7]);
            #pragma unroll
            for (int j = 0; j < 8; ++j) { ps[j] += acc2[i][j]; pq[j] += acc2[i][j] * acc2[i][j]; }
        }
        *reinterpret_cast<float4*>(&bps[rr][cg * 8])     = make_float4(ps[0], ps[1], ps[2], ps[3]);
        *reinterpret_cast<float4*>(&bps[rr][cg * 8 + 4]) = make_float4(ps[4], ps[5], ps[6], ps[7]);
        *reinterpret_cast<float4*>(&bqs[rr][cg * 8])     = make_float4(pq[0], pq[1], pq[2], pq[3]);
        *reinterpret_cast<float4*>(&bqs[rr][cg * 8 + 4]) = make_float4(pq[4], pq[5], pq[6], pq[7]);
    }
    __syncthreads();
    if (tid < 128) {
        float s = 0.f, q = 0.f;
        #pragma unroll
        for (int w = 0; w < 8; ++w) { s += bps[w][tid]; q += bqs[w][tid]; }
        size_t idx = ((size_t)bid * DD + tid) * 2;
        pA1[idx] = s; pA1[idx + 1] = q;
    }
}

// ---------------------------------------------------------------------------
__global__ __launch_bounds__(256)
void bn_reduce(const float* __restrict__ pA, int nblk, int ncol, float invN,
               const float* __restrict__ g, const float* __restrict__ be,
               float* __restrict__ sc, float* __restrict__ sh)
{
    __shared__ float rs[256], rq[256];
    int col = blockIdx.x, tid = threadIdx.x;
    float s = 0.f, q = 0.f;
    for (int i = tid; i < nblk; i += 256) {
        size_t idx = ((size_t)i * ncol + col) * 2;
        s += pA[idx]; q += pA[idx + 1];
    }
    rs[tid] = s; rq[tid] = q;
    __syncthreads();
    for (int o = 128; o > 0; o >>= 1) {
        if (tid < o) { rs[tid] += rs[tid + o]; rq[tid] += rq[tid + o]; }
        __syncthreads();
    }
    if (tid == 0) {
        float mu  = rs[0] * invN;
        float var = fmaxf(rq[0] * invN - mu * mu, 0.f);
        float inv = 1.0f / sqrtf(var + EPSV);
        float scv = g[col] * inv;
        sc[col] = scv;
        sh[col] = be[col] - mu * scv;
    }
}

__global__ __launch_bounds__(128)
void compute_pn(const float* __restrict__ p, float* __restrict__ pn)
{
    __shared__ float rs[128];
    int t = threadIdx.x;
    float v = p[t];
    rs[t] = v * v;
    __syncthreads();
    for (int o = 64; o > 0; o >>= 1) {
        if (t < o) rs[t] += rs[t + o];
        __syncthreads();
    }
    float nrm = sqrtf(rs[0]) + 1e-16f;
    pn[t] = v / nrm;
}

__global__ __launch_bounds__(128)
void pool_mlp(const float* __restrict__ r1, const float* __restrict__ sc1,
              const float* __restrict__ sh1, const float* __restrict__ pn,
              const float* __restrict__ mW1, const float* __restrict__ mb1,
              const float* __restrict__ mW2, const float* __restrict__ mb2,
              float* __restrict__ out)
{
    __shared__ float hf[16][136];
    __shared__ float sv[16];
    __shared__ float tv[16];
    __shared__ float pooled[128];
    __shared__ float y1[32];
    int tid = threadIdx.x;
    int sid = blockIdx.x;
    float scv = sc1[tid], shv = sh1[tid];
    const float* base = r1 + (size_t)sid * TT * DD;
    #pragma unroll
    for (int i = 0; i < 16; ++i)
        hf[i][tid] = base[i * DD + tid] * scv + shv;
    __syncthreads();

    {
        int r = tid >> 3, q = tid & 7;
        float s = 0.f;
        #pragma unroll
        for (int cc = 0; cc < 16; ++cc) {
            int c = q + cc * 8;
            s += hf[r][c] * pn[c];
        }
        s += __shfl_down(s, 4, 8);
        s += __shfl_down(s, 2, 8);
        s += __shfl_down(s, 1, 8);
        if (q == 0) sv[r] = s;
    }
    __syncthreads();

    if (tid < 16) {
        float si = sv[tid];
        int rank = 0;
        #pragma unroll
        for (int u = 0; u < 16; ++u) {
            float su = sv[u];
            rank += (su > si || (su == si && u < tid)) ? 1 : 0;
        }
        tv[tid] = (rank < 8) ? tanhf(si) : 0.f;
    }
    __syncthreads();

    {
        float a = 0.f;
        #pragma unroll
        for (int rr2 = 0; rr2 < 16; ++rr2)
            a += fmaxf(hf[rr2][tid] * tv[rr2], 0.f);
        pooled[tid] = a * 0.125f;
    }
    __syncthreads();

    {
        int j = tid >> 2, q = tid & 3;
        float a = 0.f;
        #pragma unroll
        for (int cc = 0; cc < 32; ++cc) {
            int c = q + cc * 4;
            a += pooled[c] * mW1[(size_t)c * 32 + j];
        }
        a += __shfl_down(a, 2, 4);
        a += __shfl_down(a, 1, 4);
        if (q == 0) y1[j] = fmaxf(a + mb1[j], 0.f);
    }
    __syncthreads();

    {
        float o = mb2[tid];
        #pragma unroll
        for (int j = 0; j < 32; ++j) o += y1[j] * mW2[j * 128 + tid];
        out[(size_t)sid * 128 + tid] = o;
    }
}

// ===========================================================================
extern "C" void kernel_launch(void* const* d_in, const int* in_sizes, int n_in,
                              void* d_out, int out_size, void* d_ws, size_t ws_size,
                              hipStream_t stream)
{
    (void)in_sizes; (void)n_in; (void)out_size; (void)ws_size;
    const float* x   = (const float*)d_in[0];
    const float* W0  = (const float*)d_in[1];
    const float* as0 = (const float*)d_in[2];
    const float* ad0 = (const float*)d_in[3];
    const float* b0  = (const float*)d_in[4];
    const float* g0  = (const float*)d_in[5];
    const float* be0 = (const float*)d_in[6];
    const float* W1  = (const float*)d_in[7];
    const float* as1 = (const float*)d_in[8];
    const float* ad1 = (const float*)d_in[9];
    const float* b1  = (const float*)d_in[10];
    const float* g1  = (const float*)d_in[11];
    const float* be1 = (const float*)d_in[12];
    const float* p   = (const float*)d_in[13];
    const float* mW1 = (const float*)d_in[14];
    const float* mb1 = (const float*)d_in[15];
    const float* mW2 = (const float*)d_in[16];
    const float* mb2 = (const float*)d_in[17];
    float* out = (float*)d_out;

    // ws layout (~151.3 MB; ws >= 155.2 MB proven by round-2 RECOMP pass)
    const size_t R1B  = (size_t)N_NODES * DD * 4;     // 134,217,728
    const size_t PA0B = 4096ull * HD * 2 * 4;         //  12,582,912
    const size_t PA1B = 4096ull * DD * 2 * 4;         //   4,194,304
    const size_t VECB = 3072 * 4;                     //      12,288

    char* ws = (char*)d_ws;
    float* r1  = (float*)ws;
    float* pA0 = (float*)(ws + R1B);
    float* pA1 = (float*)(ws + R1B + PA0B);
    float* vec = (float*)(ws + R1B + PA0B + PA1B);
    float* sc0 = vec;            // 512 floats each slot
    float* sh0 = vec + 512;
    float* sc1 = vec + 1024;
    float* sh1 = vec + 1536;
    float* pn  = vec + 2048;
    short* w0t = (short*)(ws + R1B + PA0B + PA1B + VECB);   // 3*384*128 shorts = 294,912 B

    const float invN = 1.0f / (float)N_NODES;

    prep_w0t<<<HD, 128, 0, stream>>>(W0, w0t);
    gat0_stats_mfma<<<N_NODES / 64, 256, 0, stream>>>(x, w0t, as0, ad0, b0, pA0);
    bn_reduce<<<HD, 256, 0, stream>>>(pA0, N_NODES / 64, HD, invN, g0, be0, sc0, sh0);
    compute_pn<<<1, 128, 0, stream>>>(p, pn);
    gat1_recomp<<<N_NODES / 64, 256, 0, stream>>>(x, W0, as0, ad0, b0, sc0, sh0,
                                                  W1, as1, ad1, b1, r1, pA1);
    bn_reduce<<<DD, 256, 0, stream>>>(pA1, N_NODES / 64, DD, invN, g1, be1, sc1, sh1);
    pool_mlp<<<SSTMT, 128, 0, stream>>>(r1, sc1, sh1, pn, mW1, mb1, mW2, mb2, out);
}

// Round 16
// 1067.313 us; speedup vs baseline: 1.2088x; 1.2088x over previous
//
#include <hip/hip_runtime.h>
#include <math.h>

// Problem constants (fixed by reference setup_inputs)
#define N_NODES 262144      // S*T
#define SSTMT   16384
#define TT      16
#define DD      128
#define HH      3
#define HD      384         // H*D
#define EPSV    1e-5f

// swizzled physical column for logical 4-aligned col c in row `row`
__device__ __forceinline__ int swzc(int row, int c) { return c ^ (((row >> 3) & 3) << 2); }

// ---------------------------------------------------------------------------
// stage a [64][128] fp32 tile from global into swizzled LDS layout
// ---------------------------------------------------------------------------
template<int NTHR>
__device__ __forceinline__ void stageSwz(float (*dst)[DD], const float* __restrict__ src)
{
    const int tid = threadIdx.x;
    #pragma unroll
    for (int j = 0; j < 2048 / NTHR; ++j) {
        int gi = j * NTHR + tid;
        int row = gi >> 5;
        int c4 = (gi & 31) * 4;
        *reinterpret_cast<float4*>(&dst[row][swzc(row, c4)]) =
            *reinterpret_cast<const float4*>(&src[(size_t)row * DD + c4]);
    }
}

// ---------------------------------------------------------------------------
// GEMM chunk: acc[i][j] += A[rr*8+i][kbeg+k] * B[kbeg+k][cg*8+j], k in [0,KLEN)
// A: swizzled LDS (broadcast b128 reads, conflict-free)
// B: GLOBAL (L1/L2-resident weights), 8 float4 loads per 4-k
// 256 FMA-instr per 8 ds_read_b128 -> LDS port demand 0.75.
// ---------------------------------------------------------------------------
template<int BSTR, int KLEN>
__device__ __forceinline__ void gemm8x8(const float (*A)[DD], const float* __restrict__ Bbase,
                                        int kbeg, int rr, int pad, float acc[8][8])
{
    const float* bp = Bbase + (size_t)kbeg * BSTR;
    const float* ar = &A[rr * 8][0];
    #pragma unroll 2
    for (int k = 0; k < KLEN; k += 4) {
        float4 b00 = *reinterpret_cast<const float4*>(bp);
        float4 b01 = *reinterpret_cast<const float4*>(bp + 4);
        float4 b10 = *reinterpret_cast<const float4*>(bp + BSTR);
        float4 b11 = *reinterpret_cast<const float4*>(bp + BSTR + 4);
        float4 b20 = *reinterpret_cast<const float4*>(bp + 2 * BSTR);
        float4 b21 = *reinterpret_cast<const float4*>(bp + 2 * BSTR + 4);
        float4 b30 = *reinterpret_cast<const float4*>(bp + 3 * BSTR);
        float4 b31 = *reinterpret_cast<const float4*>(bp + 3 * BSTR + 4);
        bp += 4 * (size_t)BSTR;
        const int pc = (kbeg + k) ^ pad;
        #pragma unroll
        for (int i = 0; i < 8; ++i) {
            float4 a = *reinterpret_cast<const float4*>(ar + i * DD + pc);
            acc[i][0] += a.x*b00.x; acc[i][1] += a.x*b00.y; acc[i][2] += a.x*b00.z; acc[i][3] += a.x*b00.w;
            acc[i][4] += a.x*b01.x; acc[i][5] += a.x*b01.y; acc[i][6] += a.x*b01.z; acc[i][7] += a.x*b01.w;
            acc[i][0] += a.y*b10.x; acc[i][1] += a.y*b10.y; acc[i][2] += a.y*b10.z; acc[i][3] += a.y*b10.w;
            acc[i][4] += a.y*b11.x; acc[i][5] += a.y*b11.y; acc[i][6] += a.y*b11.z; acc[i][7] += a.y*b11.w;
            acc[i][0] += a.z*b20.x; acc[i][1] += a.z*b20.y; acc[i][2] += a.z*b20.z; acc[i][3] += a.z*b20.w;
            acc[i][4] += a.z*b21.x; acc[i][5] += a.z*b21.y; acc[i][6] += a.z*b21.z; acc[i][7] += a.z*b21.w;
            acc[i][0] += a.w*b30.x; acc[i][1] += a.w*b30.y; acc[i][2] += a.w*b30.z; acc[i][3] += a.w*b30.w;
            acc[i][4] += a.w*b31.x; acc[i][5] += a.w*b31.y; acc[i][6] += a.w*b31.z; acc[i][7] += a.w*b31.w;
        }
    }
}

// ---------------------------------------------------------------------------
// In-place attention + aggregation + bias + relu on acc[8][8].
// Caller must be a full wave whose 4 row-groups are contiguous (rr base mod 4).
// ---------------------------------------------------------------------------
__device__ __forceinline__ void attnAgg(float acc[8][8],
                                        const float* __restrict__ avsP,
                                        const float* __restrict__ avdP,
                                        const float* __restrict__ bP, int rr)
{
    float4 s0 = *reinterpret_cast<const float4*>(avsP);
    float4 s1 = *reinterpret_cast<const float4*>(avsP + 4);
    float4 d0 = *reinterpret_cast<const float4*>(avdP);
    float4 d1 = *reinterpret_cast<const float4*>(avdP + 4);
    float als[8], ald[8];
    #pragma unroll
    for (int i = 0; i < 8; ++i) {
        als[i] = acc[i][0]*s0.x + acc[i][1]*s0.y + acc[i][2]*s0.z + acc[i][3]*s0.w
               + acc[i][4]*s1.x + acc[i][5]*s1.y + acc[i][6]*s1.z + acc[i][7]*s1.w;
        ald[i] = acc[i][0]*d0.x + acc[i][1]*d0.y + acc[i][2]*d0.z + acc[i][3]*d0.w
               + acc[i][4]*d1.x + acc[i][5]*d1.y + acc[i][6]*d1.z + acc[i][7]*d1.w;
    }
    #pragma unroll
    for (int m = 1; m <= 8; m <<= 1) {
        #pragma unroll
        for (int i = 0; i < 8; ++i) {
            als[i] += __shfl_xor(als[i], m);
            ald[i] += __shfl_xor(ald[i], m);
        }
    }
    float alsN = __shfl_down(als[0], 16);
    float accN[8];
    #pragma unroll
    for (int j = 0; j < 8; ++j) accN[j] = __shfl_down(acc[0][j], 16);

    float4 bb0 = *reinterpret_cast<const float4*>(bP);
    float4 bb1 = *reinterpret_cast<const float4*>(bP + 4);
    float bbv[8] = {bb0.x, bb0.y, bb0.z, bb0.w, bb1.x, bb1.y, bb1.z, bb1.w};
    const bool tail7 = (rr & 1);
    #pragma unroll
    for (int i = 0; i < 8; ++i) {
        float es = als[i] + ald[i];
        es = es > 0.f ? es : 0.2f * es;
        float aS = 1.f, aN = 0.f;
        if (!(tail7 && i == 7)) {
            float en = ((i < 7) ? als[i + 1] : alsN) + ald[i];
            en = en > 0.f ? en : 0.2f * en;
            float mx = fmaxf(es, en);
            float e1 = expf(es - mx), e2 = expf(en - mx);
            float den = e1 + e2;
            aS = e1 / den; aN = e2 / den;
        }
        #pragma unroll
        for (int j = 0; j < 8; ++j) {
            float nb = (i < 7) ? acc[i + 1][j] : accN[j];
            acc[i][j] = fmaxf(aS * acc[i][j] + aN * nb + bbv[j], 0.f);
        }
    }
}

// ---------------------------------------------------------------------------
// Pass 1: layer-0 forward for BN0 statistics only.
// 128 thr; 64 rows/block; 8x8 micro-tile; LDS 36KB.
// PER-HEAD stats flush keeps live stats at 16 regs -> peak <=128, no spill.
// ---------------------------------------------------------------------------
__global__ __launch_bounds__(128, 2)
void gat0_stats(const float* __restrict__ x, const float* __restrict__ W0,
                const float* __restrict__ as0, const float* __restrict__ ad0,
                const float* __restrict__ b0, float* __restrict__ pA0)
{
    __shared__ float xs[64][DD];
    __shared__ float bns[8][DD];

    const int tid = threadIdx.x;
    const int bid = blockIdx.x;
    const int rr = tid >> 4;
    const int cg = tid & 15;
    const int pad = (rr & 3) << 2;
    const size_t rb = (size_t)bid * 64;

    stageSwz<128>(xs, x + rb * DD);
    __syncthreads();

    for (int h = 0; h < HH; ++h) {
        float acc[8][8];
        #pragma unroll
        for (int i = 0; i < 8; ++i)
            #pragma unroll
            for (int j = 0; j < 8; ++j) acc[i][j] = 0.f;

        gemm8x8<HD, 128>(xs, W0 + h * DD + cg * 8, 0, rr, pad, acc);
        attnAgg(acc, as0 + h * DD + cg * 8, ad0 + h * DD + cg * 8, b0 + h * DD + cg * 8, rr);

        float ps[8], pq[8];
        #pragma unroll
        for (int j = 0; j < 8; ++j) { ps[j] = 0.f; pq[j] = 0.f; }
        #pragma unroll
        for (int i = 0; i < 8; ++i)
            #pragma unroll
            for (int j = 0; j < 8; ++j) {
                float o = acc[i][j];
                ps[j] += o; pq[j] += o * o;
            }

        __syncthreads();           // previous head's bns reads done
        *reinterpret_cast<float4*>(&bns[rr][cg * 8]) =
            make_float4(ps[0], ps[1], ps[2], ps[3]);
        *reinterpret_cast<float4*>(&bns[rr][cg * 8 + 4]) =
            make_float4(ps[4], ps[5], ps[6], ps[7]);
        __syncthreads();
        float sv = 0.f;
        #pragma unroll
        for (int w = 0; w < 8; ++w) sv += bns[w][tid];
        __syncthreads();
        *reinterpret_cast<float4*>(&bns[rr][cg * 8]) =
            make_float4(pq[0], pq[1], pq[2], pq[3]);
        *reinterpret_cast<float4*>(&bns[rr][cg * 8 + 4]) =
            make_float4(pq[4], pq[5], pq[6], pq[7]);
        __syncthreads();
        float qv = 0.f;
        #pragma unroll
        for (int w = 0; w < 8; ++w) qv += bns[w][tid];
        size_t idx = ((size_t)bid * HD + h * DD + tid) * 2;
        pA0[idx] = sv; pA0[idx + 1] = qv;
    }
}

// ---------------------------------------------------------------------------
// Pass 3: recompute layer-0 (BN0 applied), interleaved layer-1 GEMM per head.
// K-split + row-split combine (best measured structure, 745us).
// ---------------------------------------------------------------------------
__global__ __launch_bounds__(256, 2)
void gat1_recomp(const float* __restrict__ x, const float* __restrict__ W0,
                 const float* __restrict__ as0, const float* __restrict__ ad0,
                 const float* __restrict__ b0, const float* __restrict__ sc0,
                 const float* __restrict__ sh0, const float* __restrict__ W1,
                 const float* __restrict__ as1, const float* __restrict__ ad1,
                 const float* __restrict__ b1,
                 float* __restrict__ r1, float* __restrict__ pA1)
{
    __shared__ float xs[64][DD];
    __shared__ float hs[64][DD];
    __shared__ float bps[8][DD], bqs[8][DD];

    const int tid = threadIdx.x;
    const int bid = blockIdx.x;
    const int kh = tid >> 7;
    const int rr = (tid >> 4) & 7;
    const int cg = tid & 15;
    const int pad = (rr & 3) << 2;
    const size_t rb = (size_t)bid * 64;
    // finisher: wave0 (kh0, rr<4) and wave3 (kh1, rr>=4)
    const bool finisher = (kh == ((rr >= 4) ? 1 : 0));

    stageSwz<256>(xs, x + rb * DD);
    __syncthreads();

    float acc2[8][8];
    #pragma unroll
    for (int i = 0; i < 8; ++i)
        #pragma unroll
        for (int j = 0; j < 8; ++j) acc2[i][j] = 0.f;

    for (int h = 0; h < HH; ++h) {
        float acc[8][8];
        #pragma unroll
        for (int i = 0; i < 8; ++i)
            #pragma unroll
            for (int j = 0; j < 8; ++j) acc[i][j] = 0.f;

        gemm8x8<HD, 64>(xs, W0 + h * DD + cg * 8, kh * 64, rr, pad, acc);

        __syncthreads();
        if (!finisher) {
            #pragma unroll
            for (int i = 0; i < 8; ++i) {
                int pc = (cg * 8) ^ pad;
                *reinterpret_cast<float4*>(&hs[rr * 8 + i][pc]) =
                    make_float4(acc[i][0], acc[i][1], acc[i][2], acc[i][3]);
                *reinterpret_cast<float4*>(&hs[rr * 8 + i][pc ^ 4]) =
                    make_float4(acc[i][4], acc[i][5], acc[i][6], acc[i][7]);
            }
        }
        __syncthreads();
        if (finisher) {
            #pragma unroll
            for (int i = 0; i < 8; ++i) {
                int pc = (cg * 8) ^ pad;
                float4 p0 = *reinterpret_cast<const float4*>(&hs[rr * 8 + i][pc]);
                float4 p1 = *reinterpret_cast<const float4*>(&hs[rr * 8 + i][pc ^ 4]);
                acc[i][0] += p0.x; acc[i][1] += p0.y; acc[i][2] += p0.z; acc[i][3] += p0.w;
                acc[i][4] += p1.x; acc[i][5] += p1.y; acc[i][6] += p1.z; acc[i][7] += p1.w;
            }
            attnAgg(acc, as0 + h * DD + cg * 8, ad0 + h * DD + cg * 8, b0 + h * DD + cg * 8, rr);
            float4 sc0a = *reinterpret_cast<const float4*>(&sc0[h * DD + cg * 8]);
            float4 sc0b = *reinterpret_cast<const float4*>(&sc0[h * DD + cg * 8 + 4]);
            float4 sh0a = *reinterpret_cast<const float4*>(&sh0[h * DD + cg * 8]);
            float4 sh0b = *reinterpret_cast<const float4*>(&sh0[h * DD + cg * 8 + 4]);
            float scv[8] = {sc0a.x, sc0a.y, sc0a.z, sc0a.w, sc0b.x, sc0b.y, sc0b.z, sc0b.w};
            float shv[8] = {sh0a.x, sh0a.y, sh0a.z, sh0a.w, sh0b.x, sh0b.y, sh0b.z, sh0b.w};
            #pragma unroll
            for (int i = 0; i < 8; ++i) {
                int pc = (cg * 8) ^ pad;
                float v0 = acc[i][0] * scv[0] + shv[0];
                float v1 = acc[i][1] * scv[1] + shv[1];
                float v2 = acc[i][2] * scv[2] + shv[2];
                float v3 = acc[i][3] * scv[3] + shv[3];
                float v4 = acc[i][4] * scv[4] + shv[4];
                float v5 = acc[i][5] * scv[5] + shv[5];
                float v6 = acc[i][6] * scv[6] + shv[6];
                float v7 = acc[i][7] * scv[7] + shv[7];
                *reinterpret_cast<float4*>(&hs[rr * 8 + i][pc]) = make_float4(v0, v1, v2, v3);
                *reinterpret_cast<float4*>(&hs[rr * 8 + i][pc ^ 4]) = make_float4(v4, v5, v6, v7);
            }
        }
        __syncthreads();

        gemm8x8<DD, 64>(hs, W1 + (size_t)(h * DD) * DD + cg * 8, kh * 64, rr, pad, acc2);
    }

    __syncthreads();
    if (!finisher) {
        #pragma unroll
        for (int i = 0; i < 8; ++i) {
            int pc = (cg * 8) ^ pad;
            *reinterpret_cast<float4*>(&xs[rr * 8 + i][pc]) =
                make_float4(acc2[i][0], acc2[i][1], acc2[i][2], acc2[i][3]);
            *reinterpret_cast<float4*>(&xs[rr * 8 + i][pc ^ 4]) =
                make_float4(acc2[i][4], acc2[i][5], acc2[i][6], acc2[i][7]);
        }
    }
    __syncthreads();
    if (finisher) {
        #pragma unroll
        for (int i = 0; i < 8; ++i) {
            int pc = (cg * 8) ^ pad;
            float4 p0 = *reinterpret_cast<const float4*>(&xs[rr * 8 + i][pc]);
            float4 p1 = *reinterpret_cast<const float4*>(&xs[rr * 8 + i][pc ^ 4]);
            acc2[i][0] += p0.x; acc2[i][1] += p0.y; acc2[i][2] += p0.z; acc2[i][3] += p0.w;
            acc2[i][4] += p1.x; acc2[i][5] += p1.y; acc2[i][6] += p1.z; acc2[i][7] += p1.w;
        }
        attnAgg(acc2, as1 + cg * 8, ad1 + cg * 8, b1 + cg * 8, rr);

        float ps[8], pq[8];
        #pragma unroll
        for (int j = 0; j < 8; ++j) { ps[j] = 0.f; pq[j] = 0.f; }
        #pragma unroll
        for (int i = 0; i < 8; ++i) {
            *reinterpret_cast<float4*>(&r1[(rb + rr * 8 + i) * DD + cg * 8]) =
                make_float4(acc2[i][0], acc2[i][1], acc2[i][2], acc2[i][3]);
            *reinterpret_cast<float4*>(&r1[(rb + rr * 8 + i) * DD + cg * 8 + 4]) =
                make_float4(acc2[i][4], acc2[i][5], acc2[i][6], acc2[i][7]);
            #pragma unroll
            for (int j = 0; j < 8; ++j) { ps[j] += acc2[i][j]; pq[j] += acc2[i][j] * acc2[i][j]; }
        }
        *reinterpret_cast<float4*>(&bps[rr][cg * 8])     = make_float4(ps[0], ps[1], ps[2], ps[3]);
        *reinterpret_cast<float4*>(&bps[rr][cg * 8 + 4]) = make_float4(ps[4], ps[5], ps[6], ps[7]);
        *reinterpret_cast<float4*>(&bqs[rr][cg * 8])     = make_float4(pq[0], pq[1], pq[2], pq[3]);
        *reinterpret_cast<float4*>(&bqs[rr][cg * 8 + 4]) = make_float4(pq[4], pq[5], pq[6], pq[7]);
    }
    __syncthreads();
    if (tid < 128) {
        float s = 0.f, q = 0.f;
        #pragma unroll
        for (int w = 0; w < 8; ++w) { s += bps[w][tid]; q += bqs[w][tid]; }
        size_t idx = ((size_t)bid * DD + tid) * 2;
        pA1[idx] = s; pA1[idx + 1] = q;
    }
}

// ---------------------------------------------------------------------------
// BN stat reduction: per column, sum partials -> scale/shift
// ---------------------------------------------------------------------------
__global__ __launch_bounds__(256)
void bn_reduce(const float* __restrict__ pA, int nblk, int ncol, float invN,
               const float* __restrict__ g, const float* __restrict__ be,
               float* __restrict__ sc, float* __restrict__ sh)
{
    __shared__ float rs[256], rq[256];
    int col = blockIdx.x, tid = threadIdx.x;
    float s = 0.f, q = 0.f;
    for (int i = tid; i < nblk; i += 256) {
        size_t idx = ((size_t)i * ncol + col) * 2;
        s += pA[idx]; q += pA[idx + 1];
    }
    rs[tid] = s; rq[tid] = q;
    __syncthreads();
    for (int o = 128; o > 0; o >>= 1) {
        if (tid < o) { rs[tid] += rs[tid + o]; rq[tid] += rq[tid + o]; }
        __syncthreads();
    }
    if (tid == 0) {
        float mu  = rs[0] * invN;
        float var = fmaxf(rq[0] * invN - mu * mu, 0.f);
        float inv = 1.0f / sqrtf(var + EPSV);
        float scv = g[col] * inv;
        sc[col] = scv;
        sh[col] = be[col] - mu * scv;
    }
}

__global__ __launch_bounds__(128)
void compute_pn(const float* __restrict__ p, float* __restrict__ pn)
{
    __shared__ float rs[128];
    int t = threadIdx.x;
    float v = p[t];
    rs[t] = v * v;
    __syncthreads();
    for (int o = 64; o > 0; o >>= 1) {
        if (t < o) rs[t] += rs[t + o];
        __syncthreads();
    }
    float nrm = sqrtf(rs[0]) + 1e-16f;
    pn[t] = v / nrm;
}

// ---------------------------------------------------------------------------
// Pass 5: per-statement BN1 affine + score + top-8 + tanh-weighted relu mean
// + MLP 128->32->128
// ---------------------------------------------------------------------------
__global__ __launch_bounds__(128)
void pool_mlp(const float* __restrict__ r1, const float* __restrict__ sc1,
              const float* __restrict__ sh1, const float* __restrict__ pn,
              const float* __restrict__ mW1, const float* __restrict__ mb1,
              const float* __restrict__ mW2, const float* __restrict__ mb2,
              float* __restrict__ out)
{
    __shared__ float hf[16][136];
    __shared__ float sv[16];
    __shared__ float tv[16];
    __shared__ float pooled[128];
    __shared__ float y1[32];
    int tid = threadIdx.x;
    int sid = blockIdx.x;
    float scv = sc1[tid], shv = sh1[tid];
    const float* base = r1 + (size_t)sid * TT * DD;
    #pragma unroll
    for (int i = 0; i < 16; ++i)
        hf[i][tid] = base[i * DD + tid] * scv + shv;
    __syncthreads();

    {
        int r = tid >> 3, q = tid & 7;
        float s = 0.f;
        #pragma unroll
        for (int cc = 0; cc < 16; ++cc) {
            int c = q + cc * 8;
            s += hf[r][c] * pn[c];
        }
        s += __shfl_down(s, 4, 8);
        s += __shfl_down(s, 2, 8);
        s += __shfl_down(s, 1, 8);
        if (q == 0) sv[r] = s;
    }
    __syncthreads();

    if (tid < 16) {
        float si = sv[tid];
        int rank = 0;
        #pragma unroll
        for (int u = 0; u < 16; ++u) {
            float su = sv[u];
            rank += (su > si || (su == si && u < tid)) ? 1 : 0;
        }
        tv[tid] = (rank < 8) ? tanhf(si) : 0.f;
    }
    __syncthreads();

    {
        float a = 0.f;
        #pragma unroll
        for (int rr2 = 0; rr2 < 16; ++rr2)
            a += fmaxf(hf[rr2][tid] * tv[rr2], 0.f);
        pooled[tid] = a * 0.125f;
    }
    __syncthreads();

    {
        int j = tid >> 2, q = tid & 3;
        float a = 0.f;
        #pragma unroll
        for (int cc = 0; cc < 32; ++cc) {
            int c = q + cc * 4;
            a += pooled[c] * mW1[(size_t)c * 32 + j];
        }
        a += __shfl_down(a, 2, 4);
        a += __shfl_down(a, 1, 4);
        if (q == 0) y1[j] = fmaxf(a + mb1[j], 0.f);
    }
    __syncthreads();

    {
        float o = mb2[tid];
        #pragma unroll
        for (int j = 0; j < 32; ++j) o += y1[j] * mW2[j * 128 + tid];
        out[(size_t)sid * 128 + tid] = o;
    }
}

// ===========================================================================
extern "C" void kernel_launch(void* const* d_in, const int* in_sizes, int n_in,
                              void* d_out, int out_size, void* d_ws, size_t ws_size,
                              hipStream_t stream)
{
    (void)in_sizes; (void)n_in; (void)out_size; (void)ws_size;
    const float* x   = (const float*)d_in[0];
    const float* W0  = (const float*)d_in[1];
    const float* as0 = (const float*)d_in[2];
    const float* ad0 = (const float*)d_in[3];
    const float* b0  = (const float*)d_in[4];
    const float* g0  = (const float*)d_in[5];
    const float* be0 = (const float*)d_in[6];
    const float* W1  = (const float*)d_in[7];
    const float* as1 = (const float*)d_in[8];
    const float* ad1 = (const float*)d_in[9];
    const float* b1  = (const float*)d_in[10];
    const float* g1  = (const float*)d_in[11];
    const float* be1 = (const float*)d_in[12];
    const float* p   = (const float*)d_in[13];
    const float* mW1 = (const float*)d_in[14];
    const float* mb1 = (const float*)d_in[15];
    const float* mW2 = (const float*)d_in[16];
    const float* mb2 = (const float*)d_in[17];
    float* out = (float*)d_out;

    // ws layout (~151 MB; ws >= 156 MB proven by round-2 RECOMP pass)
    const size_t R1B  = (size_t)N_NODES * DD * 4;     // 134,217,728
    const size_t PA0B = 4096ull * HD * 2 * 4;         //  12,582,912
    const size_t PA1B = 4096ull * DD * 2 * 4;         //   4,194,304

    char* ws = (char*)d_ws;
    float* r1  = (float*)ws;
    float* pA0 = (float*)(ws + R1B);
    float* pA1 = (float*)(ws + R1B + PA0B);
    float* vec = (float*)(ws + R1B + PA0B + PA1B);
    float* sc0 = vec;            // 512 floats each slot
    float* sh0 = vec + 512;
    float* sc1 = vec + 1024;
    float* sh1 = vec + 1536;
    float* pn  = vec + 2048;

    const float invN = 1.0f / (float)N_NODES;

    gat0_stats<<<N_NODES / 64, 128, 0, stream>>>(x, W0, as0, ad0, b0, pA0);
    bn_reduce<<<HD, 256, 0, stream>>>(pA0, N_NODES / 64, HD, invN, g0, be0, sc0, sh0);
    compute_pn<<<1, 128, 0, stream>>>(p, pn);
    gat1_recomp<<<N_NODES / 64, 256, 0, stream>>>(x, W0, as0, ad0, b0, sc0, sh0,
                                                  W1, as1, ad1, b1, r1, pA1);
    bn_reduce<<<DD, 256, 0, stream>>>(pA1, N_NODES / 64, DD, invN, g1, be1, sc1, sh1);
    pool_mlp<<<SSTMT, 128, 0, stream>>>(r1, sc1, sh1, pn, mW1, mb1, mW2, mb2, out);
}

// Round 17
// 1065.947 us; speedup vs baseline: 1.2103x; 1.0013x over previous
//
#include <hip/hip_runtime.h>
#include <math.h>

// Problem constants (fixed by reference setup_inputs)
#define N_NODES 262144      // S*T
#define SSTMT   16384
#define TT      16
#define DD      128
#define HH      3
#define HD      384         // H*D
#define EPSV    1e-5f

// swizzled physical column for logical 4-aligned col c in row `row`
__device__ __forceinline__ int swzc(int row, int c) { return c ^ (((row >> 3) & 3) << 2); }

// ---------------------------------------------------------------------------
// stage a [64][128] fp32 tile from global into swizzled LDS layout
// ---------------------------------------------------------------------------
template<int NTHR>
__device__ __forceinline__ void stageSwz(float (*dst)[DD], const float* __restrict__ src)
{
    const int tid = threadIdx.x;
    #pragma unroll
    for (int j = 0; j < 2048 / NTHR; ++j) {
        int gi = j * NTHR + tid;
        int row = gi >> 5;
        int c4 = (gi & 31) * 4;
        *reinterpret_cast<float4*>(&dst[row][swzc(row, c4)]) =
            *reinterpret_cast<const float4*>(&src[(size_t)row * DD + c4]);
    }
}

// ---------------------------------------------------------------------------
// GEMM chunk: acc[i][j] += A[rr*8+i][kbeg+k] * B[kbeg+k][cg*8+j], k in [0,KLEN)
// A: swizzled LDS (broadcast b128 reads, conflict-free)
// B: GLOBAL (L1/L2-resident weights), 8 float4 loads per 4-k
// 256 FMA-instr per 8 ds_read_b128 -> LDS port demand 0.75.
// ---------------------------------------------------------------------------
template<int BSTR, int KLEN>
__device__ __forceinline__ void gemm8x8(const float (*A)[DD], const float* __restrict__ Bbase,
                                        int kbeg, int rr, int pad, float acc[8][8])
{
    const float* bp = Bbase + (size_t)kbeg * BSTR;
    const float* ar = &A[rr * 8][0];
    #pragma unroll 2
    for (int k = 0; k < KLEN; k += 4) {
        float4 b00 = *reinterpret_cast<const float4*>(bp);
        float4 b01 = *reinterpret_cast<const float4*>(bp + 4);
        float4 b10 = *reinterpret_cast<const float4*>(bp + BSTR);
        float4 b11 = *reinterpret_cast<const float4*>(bp + BSTR + 4);
        float4 b20 = *reinterpret_cast<const float4*>(bp + 2 * BSTR);
        float4 b21 = *reinterpret_cast<const float4*>(bp + 2 * BSTR + 4);
        float4 b30 = *reinterpret_cast<const float4*>(bp + 3 * BSTR);
        float4 b31 = *reinterpret_cast<const float4*>(bp + 3 * BSTR + 4);
        bp += 4 * (size_t)BSTR;
        const int pc = (kbeg + k) ^ pad;
        #pragma unroll
        for (int i = 0; i < 8; ++i) {
            float4 a = *reinterpret_cast<const float4*>(ar + i * DD + pc);
            acc[i][0] += a.x*b00.x; acc[i][1] += a.x*b00.y; acc[i][2] += a.x*b00.z; acc[i][3] += a.x*b00.w;
            acc[i][4] += a.x*b01.x; acc[i][5] += a.x*b01.y; acc[i][6] += a.x*b01.z; acc[i][7] += a.x*b01.w;
            acc[i][0] += a.y*b10.x; acc[i][1] += a.y*b10.y; acc[i][2] += a.y*b10.z; acc[i][3] += a.y*b10.w;
            acc[i][4] += a.y*b11.x; acc[i][5] += a.y*b11.y; acc[i][6] += a.y*b11.z; acc[i][7] += a.y*b11.w;
            acc[i][0] += a.z*b20.x; acc[i][1] += a.z*b20.y; acc[i][2] += a.z*b20.z; acc[i][3] += a.z*b20.w;
            acc[i][4] += a.z*b21.x; acc[i][5] += a.z*b21.y; acc[i][6] += a.z*b21.z; acc[i][7] += a.z*b21.w;
            acc[i][0] += a.w*b30.x; acc[i][1] += a.w*b30.y; acc[i][2] += a.w*b30.z; acc[i][3] += a.w*b30.w;
            acc[i][4] += a.w*b31.x; acc[i][5] += a.w*b31.y; acc[i][6] += a.w*b31.z; acc[i][7] += a.w*b31.w;
        }
    }
}

// ---------------------------------------------------------------------------
// In-place attention + aggregation + bias + relu on acc[8][8].
// Caller must be a full wave whose 4 row-groups are contiguous (rr base mod 4).
// ---------------------------------------------------------------------------
__device__ __forceinline__ void attnAgg(float acc[8][8],
                                        const float* __restrict__ avsP,
                                        const float* __restrict__ avdP,
                                        const float* __restrict__ bP, int rr)
{
    float4 s0 = *reinterpret_cast<const float4*>(avsP);
    float4 s1 = *reinterpret_cast<const float4*>(avsP + 4);
    float4 d0 = *reinterpret_cast<const float4*>(avdP);
    float4 d1 = *reinterpret_cast<const float4*>(avdP + 4);
    float als[8], ald[8];
    #pragma unroll
    for (int i = 0; i < 8; ++i) {
        als[i] = acc[i][0]*s0.x + acc[i][1]*s0.y + acc[i][2]*s0.z + acc[i][3]*s0.w
               + acc[i][4]*s1.x + acc[i][5]*s1.y + acc[i][6]*s1.z + acc[i][7]*s1.w;
        ald[i] = acc[i][0]*d0.x + acc[i][1]*d0.y + acc[i][2]*d0.z + acc[i][3]*d0.w
               + acc[i][4]*d1.x + acc[i][5]*d1.y + acc[i][6]*d1.z + acc[i][7]*d1.w;
    }
    #pragma unroll
    for (int m = 1; m <= 8; m <<= 1) {
        #pragma unroll
        for (int i = 0; i < 8; ++i) {
            als[i] += __shfl_xor(als[i], m);
            ald[i] += __shfl_xor(ald[i], m);
        }
    }
    float alsN = __shfl_down(als[0], 16);
    float accN[8];
    #pragma unroll
    for (int j = 0; j < 8; ++j) accN[j] = __shfl_down(acc[0][j], 16);

    float4 bb0 = *reinterpret_cast<const float4*>(bP);
    float4 bb1 = *reinterpret_cast<const float4*>(bP + 4);
    float bbv[8] = {bb0.x, bb0.y, bb0.z, bb0.w, bb1.x, bb1.y, bb1.z, bb1.w};
    const bool tail7 = (rr & 1);
    #pragma unroll
    for (int i = 0; i < 8; ++i) {
        float es = als[i] + ald[i];
        es = es > 0.f ? es : 0.2f * es;
        float aS = 1.f, aN = 0.f;
        if (!(tail7 && i == 7)) {
            float en = ((i < 7) ? als[i + 1] : alsN) + ald[i];
            en = en > 0.f ? en : 0.2f * en;
            float mx = fmaxf(es, en);
            float e1 = expf(es - mx), e2 = expf(en - mx);
            float den = e1 + e2;
            aS = e1 / den; aN = e2 / den;
        }
        #pragma unroll
        for (int j = 0; j < 8; ++j) {
            float nb = (i < 7) ? acc[i + 1][j] : accN[j];
            acc[i][j] = fmaxf(aS * acc[i][j] + aN * nb + bbv[j], 0.f);
        }
    }
}

// ---------------------------------------------------------------------------
// Pass 1: layer-0 forward for BN0 statistics only.
// 128 thr; 64 rows/block; 8x8 micro-tile; LDS 36KB.
// PER-HEAD stats flush keeps live stats at 16 regs -> peak <=128, no spill.
// ---------------------------------------------------------------------------
__global__ __launch_bounds__(128, 2)
void gat0_stats(const float* __restrict__ x, const float* __restrict__ W0,
                const float* __restrict__ as0, const float* __restrict__ ad0,
                const float* __restrict__ b0, float* __restrict__ pA0)
{
    __shared__ float xs[64][DD];
    __shared__ float bns[8][DD];

    const int tid = threadIdx.x;
    const int bid = blockIdx.x;
    const int rr = tid >> 4;
    const int cg = tid & 15;
    const int pad = (rr & 3) << 2;
    const size_t rb = (size_t)bid * 64;

    stageSwz<128>(xs, x + rb * DD);
    __syncthreads();

    for (int h = 0; h < HH; ++h) {
        float acc[8][8];
        #pragma unroll
        for (int i = 0; i < 8; ++i)
            #pragma unroll
            for (int j = 0; j < 8; ++j) acc[i][j] = 0.f;

        gemm8x8<HD, 128>(xs, W0 + h * DD + cg * 8, 0, rr, pad, acc);
        attnAgg(acc, as0 + h * DD + cg * 8, ad0 + h * DD + cg * 8, b0 + h * DD + cg * 8, rr);

        float ps[8], pq[8];
        #pragma unroll
        for (int j = 0; j < 8; ++j) { ps[j] = 0.f; pq[j] = 0.f; }
        #pragma unroll
        for (int i = 0; i < 8; ++i)
            #pragma unroll
            for (int j = 0; j < 8; ++j) {
                float o = acc[i][j];
                ps[j] += o; pq[j] += o * o;
            }

        __syncthreads();           // previous head's bns reads done
        *reinterpret_cast<float4*>(&bns[rr][cg * 8]) =
            make_float4(ps[0], ps[1], ps[2], ps[3]);
        *reinterpret_cast<float4*>(&bns[rr][cg * 8 + 4]) =
            make_float4(ps[4], ps[5], ps[6], ps[7]);
        __syncthreads();
        float sv = 0.f;
        #pragma unroll
        for (int w = 0; w < 8; ++w) sv += bns[w][tid];
        __syncthreads();
        *reinterpret_cast<float4*>(&bns[rr][cg * 8]) =
            make_float4(pq[0], pq[1], pq[2], pq[3]);
        *reinterpret_cast<float4*>(&bns[rr][cg * 8 + 4]) =
            make_float4(pq[4], pq[5], pq[6], pq[7]);
        __syncthreads();
        float qv = 0.f;
        #pragma unroll
        for (int w = 0; w < 8; ++w) qv += bns[w][tid];
        size_t idx = ((size_t)bid * HD + h * DD + tid) * 2;
        pA0[idx] = sv; pA0[idx + 1] = qv;
    }
}

// ---------------------------------------------------------------------------
// Pass 3: recompute layer-0 (BN0 applied), interleaved layer-1 GEMM per head.
// K-split + row-split combine (best measured structure, 745us).
// ---------------------------------------------------------------------------
__global__ __launch_bounds__(256, 2)
void gat1_recomp(const float* __restrict__ x, const float* __restrict__ W0,
                 const float* __restrict__ as0, const float* __restrict__ ad0,
                 const float* __restrict__ b0, const float* __restrict__ sc0,
                 const float* __restrict__ sh0, const float* __restrict__ W1,
                 const float* __restrict__ as1, const float* __restrict__ ad1,
                 const float* __restrict__ b1,
                 float* __restrict__ r1, float* __restrict__ pA1)
{
    __shared__ float xs[64][DD];
    __shared__ float hs[64][DD];
    __shared__ float bps[8][DD], bqs[8][DD];

    const int tid = threadIdx.x;
    const int bid = blockIdx.x;
    const int kh = tid >> 7;
    const int rr = (tid >> 4) & 7;
    const int cg = tid & 15;
    const int pad = (rr & 3) << 2;
    const size_t rb = (size_t)bid * 64;
    // finisher: wave0 (kh0, rr<4) and wave3 (kh1, rr>=4)
    const bool finisher = (kh == ((rr >= 4) ? 1 : 0));

    stageSwz<256>(xs, x + rb * DD);
    __syncthreads();

    float acc2[8][8];
    #pragma unroll
    for (int i = 0; i < 8; ++i)
        #pragma unroll
        for (int j = 0; j < 8; ++j) acc2[i][j] = 0.f;

    for (int h = 0; h < HH; ++h) {
        float acc[8][8];
        #pragma unroll
        for (int i = 0; i < 8; ++i)
            #pragma unroll
            for (int j = 0; j < 8; ++j) acc[i][j] = 0.f;

        gemm8x8<HD, 64>(xs, W0 + h * DD + cg * 8, kh * 64, rr, pad, acc);

        __syncthreads();
        if (!finisher) {
            #pragma unroll
            for (int i = 0; i < 8; ++i) {
                int pc = (cg * 8) ^ pad;
                *reinterpret_cast<float4*>(&hs[rr * 8 + i][pc]) =
                    make_float4(acc[i][0], acc[i][1], acc[i][2], acc[i][3]);
                *reinterpret_cast<float4*>(&hs[rr * 8 + i][pc ^ 4]) =
                    make_float4(acc[i][4], acc[i][5], acc[i][6], acc[i][7]);
            }
        }
        __syncthreads();
        if (finisher) {
            #pragma unroll
            for (int i = 0; i < 8; ++i) {
                int pc = (cg * 8) ^ pad;
                float4 p0 = *reinterpret_cast<const float4*>(&hs[rr * 8 + i][pc]);
                float4 p1 = *reinterpret_cast<const float4*>(&hs[rr * 8 + i][pc ^ 4]);
                acc[i][0] += p0.x; acc[i][1] += p0.y; acc[i][2] += p0.z; acc[i][3] += p0.w;
                acc[i][4] += p1.x; acc[i][5] += p1.y; acc[i][6] += p1.z; acc[i][7] += p1.w;
            }
            attnAgg(acc, as0 + h * DD + cg * 8, ad0 + h * DD + cg * 8, b0 + h * DD + cg * 8, rr);
            float4 sc0a = *reinterpret_cast<const float4*>(&sc0[h * DD + cg * 8]);
            float4 sc0b = *reinterpret_cast<const float4*>(&sc0[h * DD + cg * 8 + 4]);
            float4 sh0a = *reinterpret_cast<const float4*>(&sh0[h * DD + cg * 8]);
            float4 sh0b = *reinterpret_cast<const float4*>(&sh0[h * DD + cg * 8 + 4]);
            float scv[8] = {sc0a.x, sc0a.y, sc0a.z, sc0a.w, sc0b.x, sc0b.y, sc0b.z, sc0b.w};
            float shv[8] = {sh0a.x, sh0a.y, sh0a.z, sh0a.w, sh0b.x, sh0b.y, sh0b.z, sh0b.w};
            #pragma unroll
            for (int i = 0; i < 8; ++i) {
                int pc = (cg * 8) ^ pad;
                float v0 = acc[i][0] * scv[0] + shv[0];
                float v1 = acc[i][1] * scv[1] + shv[1];
                float v2 = acc[i][2] * scv[2] + shv[2];
                float v3 = acc[i][3] * scv[3] + shv[3];
                float v4 = acc[i][4] * scv[4] + shv[4];
                float v5 = acc[i][5] * scv[5] + shv[5];
                float v6 = acc[i][6] * scv[6] + shv[6];
                float v7 = acc[i][7] * scv[7] + shv[7];
                *reinterpret_cast<float4*>(&hs[rr * 8 + i][pc]) = make_float4(v0, v1, v2, v3);
                *reinterpret_cast<float4*>(&hs[rr * 8 + i][pc ^ 4]) = make_float4(v4, v5, v6, v7);
            }
        }
        __syncthreads();

        gemm8x8<DD, 64>(hs, W1 + (size_t)(h * DD) * DD + cg * 8, kh * 64, rr, pad, acc2);
    }

    __syncthreads();
    if (!finisher) {
        #pragma unroll
        for (int i = 0; i < 8; ++i) {
            int pc = (cg * 8) ^ pad;
            *reinterpret_cast<float4*>(&xs[rr * 8 + i][pc]) =
                make_float4(acc2[i][0], acc2[i][1], acc2[i][2], acc2[i][3]);
            *reinterpret_cast<float4*>(&xs[rr * 8 + i][pc ^ 4]) =
                make_float4(acc2[i][4], acc2[i][5], acc2[i][6], acc2[i][7]);
        }
    }
    __syncthreads();
    if (finisher) {
        #pragma unroll
        for (int i = 0; i < 8; ++i) {
            int pc = (cg * 8) ^ pad;
            float4 p0 = *reinterpret_cast<const float4*>(&xs[rr * 8 + i][pc]);
            float4 p1 = *reinterpret_cast<const float4*>(&xs[rr * 8 + i][pc ^ 4]);
            acc2[i][0] += p0.x; acc2[i][1] += p0.y; acc2[i][2] += p0.z; acc2[i][3] += p0.w;
            acc2[i][4] += p1.x; acc2[i][5] += p1.y; acc2[i][6] += p1.z; acc2[i][7] += p1.w;
        }
        attnAgg(acc2, as1 + cg * 8, ad1 + cg * 8, b1 + cg * 8, rr);

        float ps[8], pq[8];
        #pragma unroll
        for (int j = 0; j < 8; ++j) { ps[j] = 0.f; pq[j] = 0.f; }
        #pragma unroll
        for (int i = 0; i < 8; ++i) {
            *reinterpret_cast<float4*>(&r1[(rb + rr * 8 + i) * DD + cg * 8]) =
                make_float4(acc2[i][0], acc2[i][1], acc2[i][2], acc2[i][3]);
            *reinterpret_cast<float4*>(&r1[(rb + rr * 8 + i) * DD + cg * 8 + 4]) =
                make_float4(acc2[i][4], acc2[i][5], acc2[i][6], acc2[i][7]);
            #pragma unroll
            for (int j = 0; j < 8; ++j) { ps[j] += acc2[i][j]; pq[j] += acc2[i][j] * acc2[i][j]; }
        }
        *reinterpret_cast<float4*>(&bps[rr][cg * 8])     = make_float4(ps[0], ps[1], ps[2], ps[3]);
        *reinterpret_cast<float4*>(&bps[rr][cg * 8 + 4]) = make_float4(ps[4], ps[5], ps[6], ps[7]);
        *reinterpret_cast<float4*>(&bqs[rr][cg * 8])     = make_float4(pq[0], pq[1], pq[2], pq[3]);
        *reinterpret_cast<float4*>(&bqs[rr][cg * 8 + 4]) = make_float4(pq[4], pq[5], pq[6], pq[7]);
    }
    __syncthreads();
    if (tid < 128) {
        float s = 0.f, q = 0.f;
        #pragma unroll
        for (int w = 0; w < 8; ++w) { s += bps[w][tid]; q += bqs[w][tid]; }
        size_t idx = ((size_t)bid * DD + tid) * 2;
        pA1[idx] = s; pA1[idx + 1] = q;
    }
}

// ---------------------------------------------------------------------------
// BN stat reduction: per column, sum partials -> scale/shift
// ---------------------------------------------------------------------------
__global__ __launch_bounds__(256)
void bn_reduce(const float* __restrict__ pA, int nblk, int ncol, float invN,
               const float* __restrict__ g, const float* __restrict__ be,
               float* __restrict__ sc, float* __restrict__ sh)
{
    __shared__ float rs[256], rq[256];
    int col = blockIdx.x, tid = threadIdx.x;
    float s = 0.f, q = 0.f;
    for (int i = tid; i < nblk; i += 256) {
        size_t idx = ((size_t)i * ncol + col) * 2;
        s += pA[idx]; q += pA[idx + 1];
    }
    rs[tid] = s; rq[tid] = q;
    __syncthreads();
    for (int o = 128; o > 0; o >>= 1) {
        if (tid < o) { rs[tid] += rs[tid + o]; rq[tid] += rq[tid + o]; }
        __syncthreads();
    }
    if (tid == 0) {
        float mu  = rs[0] * invN;
        float var = fmaxf(rq[0] * invN - mu * mu, 0.f);
        float inv = 1.0f / sqrtf(var + EPSV);
        float scv = g[col] * inv;
        sc[col] = scv;
        sh[col] = be[col] - mu * scv;
    }
}

__global__ __launch_bounds__(128)
void compute_pn(const float* __restrict__ p, float* __restrict__ pn)
{
    __shared__ float rs[128];
    int t = threadIdx.x;
    float v = p[t];
    rs[t] = v * v;
    __syncthreads();
    for (int o = 64; o > 0; o >>= 1) {
        if (t < o) rs[t] += rs[t + o];
        __syncthreads();
    }
    float nrm = sqrtf(rs[0]) + 1e-16f;
    pn[t] = v / nrm;
}

// ---------------------------------------------------------------------------
// Pass 5: per-statement BN1 affine + score + top-8 + tanh-weighted relu mean
// + MLP 128->32->128.  TWO statements per 256-thread block (full waves, half
// the blocks of the 128-thread/1-stmt version).
// ---------------------------------------------------------------------------
__global__ __launch_bounds__(256)
void pool_mlp2(const float* __restrict__ r1, const float* __restrict__ sc1,
               const float* __restrict__ sh1, const float* __restrict__ pn,
               const float* __restrict__ mW1, const float* __restrict__ mb1,
               const float* __restrict__ mW2, const float* __restrict__ mb2,
               float* __restrict__ out)
{
    __shared__ float hf[2][16][136];
    __shared__ float sv[2][16];
    __shared__ float tv[2][16];
    __shared__ float pooled[2][128];
    __shared__ float y1[2][32];
    const int tid = threadIdx.x;
    const int st  = tid >> 7;          // statement slot 0/1
    const int lc  = tid & 127;         // local thread within statement
    const size_t sid = (size_t)blockIdx.x * 2 + st;

    float scv = sc1[lc], shv = sh1[lc];
    const float* base = r1 + sid * TT * DD;
    #pragma unroll
    for (int i = 0; i < 16; ++i)
        hf[st][i][lc] = base[i * DD + lc] * scv + shv;
    __syncthreads();

    {
        int r = lc >> 3, q = lc & 7;
        float s = 0.f;
        #pragma unroll
        for (int cc = 0; cc < 16; ++cc) {
            int c = q + cc * 8;
            s += hf[st][r][c] * pn[c];
        }
        s += __shfl_down(s, 4, 8);
        s += __shfl_down(s, 2, 8);
        s += __shfl_down(s, 1, 8);
        if (q == 0) sv[st][r] = s;
    }
    __syncthreads();

    if (lc < 16) {
        float si = sv[st][lc];
        int rank = 0;
        #pragma unroll
        for (int u = 0; u < 16; ++u) {
            float su = sv[st][u];
            rank += (su > si || (su == si && u < lc)) ? 1 : 0;
        }
        tv[st][lc] = (rank < 8) ? tanhf(si) : 0.f;
    }
    __syncthreads();

    {
        float a = 0.f;
        #pragma unroll
        for (int rr2 = 0; rr2 < 16; ++rr2)
            a += fmaxf(hf[st][rr2][lc] * tv[st][rr2], 0.f);
        pooled[st][lc] = a * 0.125f;
    }
    __syncthreads();

    {
        int j = lc >> 2, q = lc & 3;
        float a = 0.f;
        #pragma unroll
        for (int cc = 0; cc < 32; ++cc) {
            int c = q + cc * 4;
            a += pooled[st][c] * mW1[(size_t)c * 32 + j];
        }
        a += __shfl_down(a, 2, 4);
        a += __shfl_down(a, 1, 4);
        if (q == 0) y1[st][j] = fmaxf(a + mb1[j], 0.f);
    }
    __syncthreads();

    {
        float o = mb2[lc];
        #pragma unroll
        for (int j = 0; j < 32; ++j) o += y1[st][j] * mW2[j * 128 + lc];
        out[sid * 128 + lc] = o;
    }
}

// ===========================================================================
extern "C" void kernel_launch(void* const* d_in, const int* in_sizes, int n_in,
                              void* d_out, int out_size, void* d_ws, size_t ws_size,
                              hipStream_t stream)
{
    (void)in_sizes; (void)n_in; (void)out_size; (void)ws_size;
    const float* x   = (const float*)d_in[0];
    const float* W0  = (const float*)d_in[1];
    const float* as0 = (const float*)d_in[2];
    const float* ad0 = (const float*)d_in[3];
    const float* b0  = (const float*)d_in[4];
    const float* g0  = (const float*)d_in[5];
    const float* be0 = (const float*)d_in[6];
    const float* W1  = (const float*)d_in[7];
    const float* as1 = (const float*)d_in[8];
    const float* ad1 = (const float*)d_in[9];
    const float* b1  = (const float*)d_in[10];
    const float* g1  = (const float*)d_in[11];
    const float* be1 = (const float*)d_in[12];
    const float* p   = (const float*)d_in[13];
    const float* mW1 = (const float*)d_in[14];
    const float* mb1 = (const float*)d_in[15];
    const float* mW2 = (const float*)d_in[16];
    const float* mb2 = (const float*)d_in[17];
    float* out = (float*)d_out;

    // ws layout (~151 MB; ws >= 156 MB proven by round-2 RECOMP pass)
    const size_t R1B  = (size_t)N_NODES * DD * 4;     // 134,217,728
    const size_t PA0B = 4096ull * HD * 2 * 4;         //  12,582,912
    const size_t PA1B = 4096ull * DD * 2 * 4;         //   4,194,304

    char* ws = (char*)d_ws;
    float* r1  = (float*)ws;
    float* pA0 = (float*)(ws + R1B);
    float* pA1 = (float*)(ws + R1B + PA0B);
    float* vec = (float*)(ws + R1B + PA0B + PA1B);
    float* sc0 = vec;            // 512 floats each slot
    float* sh0 = vec + 512;
    float* sc1 = vec + 1024;
    float* sh1 = vec + 1536;
    float* pn  = vec + 2048;

    const float invN = 1.0f / (float)N_NODES;

    gat0_stats<<<N_NODES / 64, 128, 0, stream>>>(x, W0, as0, ad0, b0, pA0);
    bn_reduce<<<HD, 256, 0, stream>>>(pA0, N_NODES / 64, HD, invN, g0, be0, sc0, sh0);
    compute_pn<<<1, 128, 0, stream>>>(p, pn);
    gat1_recomp<<<N_NODES / 64, 256, 0, stream>>>(x, W0, as0, ad0, b0, sc0, sh0,
                                                  W1, as1, ad1, b1, r1, pA1);
    bn_reduce<<<DD, 256, 0, stream>>>(pA1, N_NODES / 64, DD, invN, g1, be1, sc1, sh1);
    pool_mlp2<<<SSTMT / 2, 256, 0, stream>>>(r1, sc1, sh1, pn, mW1, mb1, mW2, mb2, out);
}